// Round 3
// baseline (149.003 us; speedup 1.0000x reference)
//
#include <hip/hip_runtime.h>

#define BATCH   8192
#define SDIM    64
#define HDIM    128
#define NB      4      // batch rows per block
#define RG      2      // row-groups per block (threads per h = RG)
#define UNFOLDS 4
// block = HDIM*RG = 256 threads = 4 waves; each thread handles NB/RG = 2 rows

typedef float f32x2 __attribute__((ext_vector_type(2)));

__device__ __forceinline__ f32x2 sigmoid2(f32x2 z) {
    // z = -log2e * sig * (x - mu); returns 1/(1+exp2(z))
    f32x2 e;
    e.x = __builtin_amdgcn_exp2f(z.x);
    e.y = __builtin_amdgcn_exp2f(z.y);
    f32x2 d = e + (f32x2){1.0f, 1.0f};
    f32x2 r;
    r.x = __builtin_amdgcn_rcpf(d.x);
    r.y = __builtin_amdgcn_rcpf(d.y);
    return r;
}

__global__ __launch_bounds__(HDIM * RG) void ltc_kernel(
    const float* __restrict__ input,    // [B,S]
    const float* __restrict__ hidden,   // [B,H]
    const float* __restrict__ s_mu,     // [S,H]
    const float* __restrict__ s_sig,    // [S,H]
    const float* __restrict__ s_W,      // [S,H]
    const float* __restrict__ h_mu,     // [H,H]
    const float* __restrict__ h_sig,    // [H,H]
    const float* __restrict__ h_W,      // [H,H]
    const float* __restrict__ w_tau,    // [H]
    const float* __restrict__ w_A,      // [H]
    const float* __restrict__ elapsed,  // [1]
    float* __restrict__ out)            // [B,H]
{
    const int tid = threadIdx.x;
    const int h   = tid & (HDIM - 1);    // 0..127 output feature
    const int g   = tid >> 7;            // row-group 0/1
    const int r0  = 2 * g;
    const int r1  = 2 * g + 1;
    const int b0  = blockIdx.x * NB;     // batch tile base

    __shared__ float st [NB][HDIM];      // current state for NB rows
    __shared__ float xin[NB][SDIM];      // input rows

    const float LOG2E = 1.4426950408889634f;

    // stage NB input rows (NB*SDIM = 256 floats, 256 threads -> 1 each)
    {
        int nb = tid >> 6;
        int s  = tid & (SDIM - 1);
        xin[nb][s] = input[(b0 + nb) * SDIM + s];
    }
    // stage initial hidden state (NB*HDIM = 512 floats, 256 threads -> 2 each)
    #pragma unroll
    for (int i = 0; i < (NB * HDIM) / (HDIM * RG); ++i) {
        int idx = i * (HDIM * RG) + tid;
        int nb  = idx >> 7;
        int hh  = idx & (HDIM - 1);
        st[nb][hh] = hidden[(b0 + nb) * HDIM + hh];
    }
    __syncthreads();

    const float dt = elapsed[0] * (1.0f / UNFOLDS);

    // ---- sensory activation for this thread's 2 rows ----
    f32x2 sens = {0.0f, 0.0f};
    for (int s = 0; s < SDIM; ++s) {
        float mu = s_mu [s * HDIM + h];
        float sg = s_sig[s * HDIM + h];
        float w  = s_W  [s * HDIM + h];
        float a  = -LOG2E * sg;
        float c  = -a * mu;
        f32x2 av = {a, a}, cv = {c, c}, wv = {w, w};
        f32x2 x  = {xin[r0][s], xin[r1][s]};           // LDS broadcast within wave
        f32x2 r  = sigmoid2(__builtin_elementwise_fma(x, av, cv));
        sens = __builtin_elementwise_fma(wv, r, sens);
    }

    const float wT  = w_tau[h];
    const float wA  = w_A[h];
    const float dA  = dt * wA;
    const float dT1 = fmaf(dt, wT, 1.0f) + 1e-8f;   // 1 + dt*w_tau + EPS
    const f32x2 dAv  = {dA, dA};
    const f32x2 dtv  = {dt, dt};
    const f32x2 dT1v = {dT1, dT1};

    // ---- ODE unfolds ----
    for (int it = 0; it < UNFOLDS; ++it) {
        f32x2 acc = sens;

        for (int p = 0; p < HDIM; ++p) {
            float mu = h_mu [p * HDIM + h];
            float sg = h_sig[p * HDIM + h];
            float w  = h_W  [p * HDIM + h];
            float a  = -LOG2E * sg;
            float c  = -a * mu;
            f32x2 av = {a, a}, cv = {c, c}, wv = {w, w};
            f32x2 x  = {st[r0][p], st[r1][p]};          // broadcast within wave
            f32x2 r  = sigmoid2(__builtin_elementwise_fma(x, av, cv));
            acc = __builtin_elementwise_fma(wv, r, acc);
        }

        // new state = (st + dA*resp) / (1 + dt*w_tau + dt*resp + eps)
        f32x2 sx  = {st[r0][h], st[r1][h]};
        f32x2 num = __builtin_elementwise_fma(dAv, acc, sx);
        f32x2 den = __builtin_elementwise_fma(dtv, acc, dT1v);
        f32x2 ns;
        ns.x = num.x * __builtin_amdgcn_rcpf(den.x);
        ns.y = num.y * __builtin_amdgcn_rcpf(den.y);

        __syncthreads();                 // all reads of st done before overwrite
        st[r0][h] = ns.x;
        st[r1][h] = ns.y;
        __syncthreads();                 // writes visible before next unfold
    }

    // ---- output ----
    out[(b0 + r0) * HDIM + h] = st[r0][h];
    out[(b0 + r1) * HDIM + h] = st[r1][h];
}

extern "C" void kernel_launch(void* const* d_in, const int* in_sizes, int n_in,
                              void* d_out, int out_size, void* d_ws, size_t ws_size,
                              hipStream_t stream) {
    const float* input   = (const float*)d_in[0];
    const float* hidden  = (const float*)d_in[1];
    const float* s_mu    = (const float*)d_in[2];
    const float* s_sig   = (const float*)d_in[3];
    const float* s_W     = (const float*)d_in[4];
    const float* h_mu    = (const float*)d_in[5];
    const float* h_sig   = (const float*)d_in[6];
    const float* h_W     = (const float*)d_in[7];
    const float* w_tau   = (const float*)d_in[8];
    const float* w_A     = (const float*)d_in[9];
    const float* elapsed = (const float*)d_in[10];
    float* out = (float*)d_out;

    dim3 grid(BATCH / NB);
    dim3 block(HDIM * RG);
    ltc_kernel<<<grid, block, 0, stream>>>(input, hidden,
                                           s_mu, s_sig, s_W,
                                           h_mu, h_sig, h_W,
                                           w_tau, w_A, elapsed, out);
}

// Round 4
// 117.319 us; speedup vs baseline: 1.2701x; 1.2701x over previous
//
#include <hip/hip_runtime.h>

#define BATCH   8192
#define SDIM    64
#define HDIM    128
#define NB      8      // batch rows per block (4 per thread, 2 row-groups)
#define UNFOLDS 4

typedef float f32x2 __attribute__((ext_vector_type(2)));
typedef float f32x4 __attribute__((ext_vector_type(4)));

__device__ __forceinline__ f32x2 sigmoid2(f32x2 z) {
    // z = -log2e * sig * (x - mu); returns 1/(1+exp2(z))
    f32x2 e;
    e.x = __builtin_amdgcn_exp2f(z.x);
    e.y = __builtin_amdgcn_exp2f(z.y);
    f32x2 d = e + (f32x2){1.0f, 1.0f};
    f32x2 r;
    r.x = __builtin_amdgcn_rcpf(d.x);
    r.y = __builtin_amdgcn_rcpf(d.y);
    return r;
}

// Pack {a, c, w, 0} per synapse so the hot loop does ONE dwordx4 load
// instead of 3 scalar loads + 2 muls.  a = -log2e*sigma, c = -a*mu.
__global__ __launch_bounds__(256) void prep_kernel(
    const float* __restrict__ s_mu, const float* __restrict__ s_sig,
    const float* __restrict__ s_W,
    const float* __restrict__ h_mu, const float* __restrict__ h_sig,
    const float* __restrict__ h_W,
    f32x4* __restrict__ hpk, f32x4* __restrict__ spk)
{
    const float LOG2E = 1.4426950408889634f;
    int i = blockIdx.x * 256 + threadIdx.x;
    if (i < HDIM * HDIM) {
        float a = -LOG2E * h_sig[i];
        hpk[i] = (f32x4){a, -a * h_mu[i], h_W[i], 0.0f};
    }
    if (i < SDIM * HDIM) {
        float a = -LOG2E * s_sig[i];
        spk[i] = (f32x4){a, -a * s_mu[i], s_W[i], 0.0f};
    }
}

__global__ __launch_bounds__(256) void ltc_main(
    const float* __restrict__ input,    // [B,S]
    const float* __restrict__ hidden,   // [B,H]
    const f32x4* __restrict__ spk,      // [S,H] packed {a,c,w,0}
    const f32x4* __restrict__ hpk,      // [H,H] packed {a,c,w,0}
    const float* __restrict__ w_tau,    // [H]
    const float* __restrict__ w_A,      // [H]
    const float* __restrict__ elapsed,  // [1]
    float* __restrict__ out)            // [B,H]
{
    const int tid = threadIdx.x;
    const int h   = tid & (HDIM - 1);    // output feature
    const int g   = tid >> 7;            // row-group 0/1 -> rows 4g..4g+3
    const int b0  = blockIdx.x * NB;

    // TRANSPOSED tiles: [pos][row] so one ds_read_b128 = 4 rows (broadcast).
    __shared__ float st [HDIM][NB];      // 4 KB
    __shared__ float xin[SDIM][NB];      // 2 KB

    for (int i = tid; i < NB * SDIM; i += 256) {
        int r = i >> 6, s = i & (SDIM - 1);
        xin[s][r] = input[(b0 + r) * SDIM + s];
    }
    for (int i = tid; i < NB * HDIM; i += 256) {
        int r = i >> 7, p = i & (HDIM - 1);
        st[p][r] = hidden[(b0 + r) * HDIM + p];
    }
    __syncthreads();

    const float dt = elapsed[0] * (1.0f / UNFOLDS);

    // ---- sensory activation for this thread's 4 rows ----
    f32x2 sens0 = {0.0f, 0.0f}, sens1 = {0.0f, 0.0f};
    #pragma unroll 8
    for (int s = 0; s < SDIM; ++s) {
        f32x4 P = spk[s * HDIM + h];                 // one dwordx4
        f32x4 x = *(const f32x4*)&xin[s][g * 4];     // one ds_read_b128 (broadcast)
        f32x2 av = {P.x, P.x}, cv = {P.y, P.y}, wv = {P.z, P.z};
        f32x2 r0 = sigmoid2(__builtin_elementwise_fma(x.xy, av, cv));
        f32x2 r1 = sigmoid2(__builtin_elementwise_fma(x.zw, av, cv));
        sens0 = __builtin_elementwise_fma(wv, r0, sens0);
        sens1 = __builtin_elementwise_fma(wv, r1, sens1);
    }

    const float wT  = w_tau[h];
    const float wA  = w_A[h];
    const float dA  = dt * wA;
    const float dT1 = fmaf(dt, wT, 1.0f) + 1e-8f;   // 1 + dt*w_tau + EPS
    const f32x2 dAv  = {dA, dA};
    const f32x2 dtv  = {dt, dt};
    const f32x2 dT1v = {dT1, dT1};

    f32x4 ns;

    // ---- ODE unfolds ----
    for (int it = 0; it < UNFOLDS; ++it) {
        f32x2 acc0 = sens0, acc1 = sens1;

        #pragma unroll 8
        for (int p = 0; p < HDIM; ++p) {
            f32x4 P = hpk[p * HDIM + h];             // one dwordx4
            f32x4 x = *(const f32x4*)&st[p][g * 4];  // one ds_read_b128 (broadcast)
            f32x2 av = {P.x, P.x}, cv = {P.y, P.y}, wv = {P.z, P.z};
            f32x2 r0 = sigmoid2(__builtin_elementwise_fma(x.xy, av, cv));
            f32x2 r1 = sigmoid2(__builtin_elementwise_fma(x.zw, av, cv));
            acc0 = __builtin_elementwise_fma(wv, r0, acc0);
            acc1 = __builtin_elementwise_fma(wv, r1, acc1);
        }

        // new state = (st + dA*resp) / (1 + dt*w_tau + dt*resp + eps)
        f32x4 old = *(const f32x4*)&st[h][g * 4];
        f32x2 n0 = __builtin_elementwise_fma(dAv, acc0, old.xy);
        f32x2 n1 = __builtin_elementwise_fma(dAv, acc1, old.zw);
        f32x2 d0 = __builtin_elementwise_fma(dtv, acc0, dT1v);
        f32x2 d1 = __builtin_elementwise_fma(dtv, acc1, dT1v);
        ns.x = n0.x * __builtin_amdgcn_rcpf(d0.x);
        ns.y = n0.y * __builtin_amdgcn_rcpf(d0.y);
        ns.z = n1.x * __builtin_amdgcn_rcpf(d1.x);
        ns.w = n1.y * __builtin_amdgcn_rcpf(d1.y);

        __syncthreads();                 // all reads of st done before overwrite
        *(f32x4*)&st[h][g * 4] = ns;
        __syncthreads();                 // writes visible before next unfold
    }

    // ---- output: this thread OWNS rows 4g..4g+3 at feature h ----
    out[(b0 + g * 4 + 0) * HDIM + h] = ns.x;
    out[(b0 + g * 4 + 1) * HDIM + h] = ns.y;
    out[(b0 + g * 4 + 2) * HDIM + h] = ns.z;
    out[(b0 + g * 4 + 3) * HDIM + h] = ns.w;
}

extern "C" void kernel_launch(void* const* d_in, const int* in_sizes, int n_in,
                              void* d_out, int out_size, void* d_ws, size_t ws_size,
                              hipStream_t stream) {
    const float* input   = (const float*)d_in[0];
    const float* hidden  = (const float*)d_in[1];
    const float* s_mu    = (const float*)d_in[2];
    const float* s_sig   = (const float*)d_in[3];
    const float* s_W     = (const float*)d_in[4];
    const float* h_mu    = (const float*)d_in[5];
    const float* h_sig   = (const float*)d_in[6];
    const float* h_W     = (const float*)d_in[7];
    const float* w_tau   = (const float*)d_in[8];
    const float* w_A     = (const float*)d_in[9];
    const float* elapsed = (const float*)d_in[10];
    float* out = (float*)d_out;

    // workspace: hpk [H*H] float4 (256 KB) then spk [S*H] float4 (128 KB)
    f32x4* hpk = (f32x4*)d_ws;
    f32x4* spk = hpk + HDIM * HDIM;

    prep_kernel<<<dim3((HDIM * HDIM + 255) / 256), dim3(256), 0, stream>>>(
        s_mu, s_sig, s_W, h_mu, h_sig, h_W, hpk, spk);

    ltc_main<<<dim3(BATCH / NB), dim3(256), 0, stream>>>(
        input, hidden, spk, hpk, w_tau, w_A, elapsed, out);
}